// Round 6
// baseline (247.481 us; speedup 1.0000x reference)
//
#include <hip/hip_runtime.h>

namespace {

constexpr int NCOL  = 3;
constexpr int N_IN  = 4;
constexpr int N_OUT = 8;
constexpr int T_W   = 37;
constexpr int NB    = 4;
constexpr int NX    = 16384;
constexpr int MAT   = 18;                 // floats per complex 3x3
constexpr int SITES = NB * NX;            // 65536
constexpr int NTHREADS = SITES * 6;       // (site, column j, half h) = 393216
constexpr int OUT_U = SITES * 4 * MAT;    // floats of output-0 (u passthrough)

__device__ constexpr int SH[4] = {11, 8, 4, 0};
__device__ constexpr int DD[4] = {8, 8, 16, 16};
__device__ constexpr int SS[4] = {2048, 256, 16, 1};

// Matrix base = 72 bytes * idx: 16B-alignment parity decided by idx&1 (compile-time).
template<int PAR>
__device__ __forceinline__ void load_mat18(const float* __restrict__ p, float* M) {
    if constexpr (PAR == 0) {
        float4 q0 = *(const float4*)(p + 0);
        float4 q1 = *(const float4*)(p + 4);
        float4 q2 = *(const float4*)(p + 8);
        float4 q3 = *(const float4*)(p + 12);
        float2 q4 = *(const float2*)(p + 16);
        M[0]=q0.x;  M[1]=q0.y;  M[2]=q0.z;  M[3]=q0.w;
        M[4]=q1.x;  M[5]=q1.y;  M[6]=q1.z;  M[7]=q1.w;
        M[8]=q2.x;  M[9]=q2.y;  M[10]=q2.z; M[11]=q2.w;
        M[12]=q3.x; M[13]=q3.y; M[14]=q3.z; M[15]=q3.w;
        M[16]=q4.x; M[17]=q4.y;
    } else {
        float2 q4 = *(const float2*)(p + 0);
        float4 q0 = *(const float4*)(p + 2);
        float4 q1 = *(const float4*)(p + 6);
        float4 q2 = *(const float4*)(p + 10);
        float4 q3 = *(const float4*)(p + 14);
        M[0]=q4.x;  M[1]=q4.y;
        M[2]=q0.x;  M[3]=q0.y;  M[4]=q0.z;  M[5]=q0.w;
        M[6]=q1.x;  M[7]=q1.y;  M[8]=q1.z;  M[9]=q1.w;
        M[10]=q2.x; M[11]=q2.y; M[12]=q2.z; M[13]=q2.w;
        M[14]=q3.x; M[15]=q3.y; M[16]=q3.z; M[17]=q3.w;
    }
}

// standalone u -> out passthrough copy (keeps main kernel lean)
__global__ __launch_bounds__(256) void copy_kernel(
    const float4* __restrict__ u4, float4* __restrict__ o4)
{
    const int gid = blockIdx.x * 256 + threadIdx.x;
#pragma unroll
    for (int k = 0; k < 4; ++k) {
        int idx = gid + k * (OUT_U / 16);   // OUT_U/4 float4 total, 4 per thread
        o4[idx] = u4[idx];
    }
}

__global__ __launch_bounds__(256) void lconv_kernel(
    const float* __restrict__ u,
    const float* __restrict__ w,
    const float* __restrict__ wgt,
    float* __restrict__ out)
{
    __shared__ float wT[T_W][N_OUT];
    const int tid = threadIdx.x;
    for (int idx = tid; idx < T_W * N_OUT; idx += 256) {
        wT[idx >> 3][idx & 7] = wgt[(idx & 7) * T_W + (idx >> 3)];
    }
    __syncthreads();

    const int gid = blockIdx.x * 256 + tid;
    const int h   = gid & 1;       // which v-pair: h=0 -> v{0,1}, h=1 -> v{2,3}
    const int sj  = gid >> 1;
    const int j   = sj % 3;        // matrix column this thread owns
    const int bs  = sj / 3;        // b*NX + x
    const int x   = bs & (NX - 1);

    const float* __restrict__ ubase = u + (size_t)bs * (4 * MAT);
    const float* __restrict__ wbase = w + (size_t)bs * (N_IN * MAT);

    float acc[N_OUT][NCOL][2];
#pragma unroll
    for (int uo = 0; uo < N_OUT; ++uo)
#pragma unroll
        for (int i = 0; i < NCOL; ++i) { acc[uo][i][0] = 0.f; acc[uo][i][1] = 0.f; }

    // ---- term 0 (w itself): this thread covers v = 2h, 2h+1 ----
#pragma unroll
    for (int t = 0; t < 2; ++t) {
        const int v = 2 * h + t;   // parity = t (2h even) -> addressing only
        float4 lo = *(const float4*)&wT[v][0];
        float4 hi = *(const float4*)&wT[v][4];
        const float cw[8] = {lo.x, lo.y, lo.z, lo.w, hi.x, hi.y, hi.z, hi.w};
#pragma unroll
        for (int i = 0; i < NCOL; ++i) {
            float2 e = *(const float2*)(wbase + v * MAT + (i * NCOL + j) * 2);
#pragma unroll
            for (int uo = 0; uo < N_OUT; ++uo) {
                acc[uo][i][0] = fmaf(cw[uo], e.x, acc[uo][i][0]);
                acc[uo][i][1] = fmaf(cw[uo], e.y, acc[uo][i][1]);
            }
        }
    }

    // ---- transported terms: 4 axes x 2 orientations, 2 v's each ----
#pragma unroll
    for (int a = 0; a < 4; ++a) {
        const int ca = (x >> SH[a]) & (DD[a] - 1);
        const int xp = (ca == DD[a] - 1) ? x - (DD[a] - 1) * SS[a] : x + SS[a];
        const int xm = (ca == 0)         ? x + (DD[a] - 1) * SS[a] : x - SS[a];
        const int bsp = bs - x + xp;
        const int bsm = bs - x + xm;

        // ---- orientation +1: U = u(x,a); neighbor w at bsp ----
        {
            const float* __restrict__ Up = ubase + a * MAT;
            float U[MAT];
            if ((a & 1) == 0) load_mat18<0>(Up, U);
            else              load_mat18<1>(Up, U);

            // d = conj(row j of U) — from memory (L1 broadcast), no reg indexing
            float vr[3], vi[3];
#pragma unroll
            for (int k = 0; k < 3; ++k) {
                float2 e = *(const float2*)(Up + (j * NCOL + k) * 2);
                vr[k] = e.x;
                vi[k] = -e.y;
            }
            const float* __restrict__ wn = w + (size_t)bsp * (N_IN * MAT);
#pragma unroll
            for (int t = 0; t < 2; ++t) {
                const int v = 2 * h + t;
                float Wn[MAT];
                if ((t & 1) == 0) { if (h == 0) load_mat18<0>(wn + 0*MAT, Wn); else load_mat18<0>(wn + 2*MAT, Wn); }
                else              { if (h == 0) load_mat18<1>(wn + 1*MAT, Wn); else load_mat18<1>(wn + 3*MAT, Wn); }

                float yr[3], yi[3];
#pragma unroll
                for (int i = 0; i < NCOL; ++i) {
                    float sr = 0.f, si = 0.f;
#pragma unroll
                    for (int k = 0; k < NCOL; ++k) {
                        float wr = Wn[(i*3+k)*2], wi = Wn[(i*3+k)*2+1];
                        sr = fmaf(wr, vr[k], sr); sr = fmaf(-wi, vi[k], sr);
                        si = fmaf(wr, vi[k], si); si = fmaf(wi, vr[k], si);
                    }
                    yr[i] = sr; yi[i] = si;
                }
                float cr[3], ci[3];
#pragma unroll
                for (int i = 0; i < NCOL; ++i) {
                    float sr = 0.f, si = 0.f;
#pragma unroll
                    for (int k = 0; k < NCOL; ++k) {
                        float ur = U[(i*3+k)*2], ui = U[(i*3+k)*2+1];
                        sr = fmaf(ur, yr[k], sr); sr = fmaf(-ui, yi[k], sr);
                        si = fmaf(ur, yi[k], si); si = fmaf(ui, yr[k], si);
                    }
                    cr[i] = sr; ci[i] = si;
                }
                const int ch = (1 + a) * 4 + v;
                float4 lo = *(const float4*)&wT[ch][0];
                float4 hi = *(const float4*)&wT[ch][4];
                const float cw[8] = {lo.x, lo.y, lo.z, lo.w, hi.x, hi.y, hi.z, hi.w};
#pragma unroll
                for (int uo = 0; uo < N_OUT; ++uo)
#pragma unroll
                    for (int i = 0; i < NCOL; ++i) {
                        acc[uo][i][0] = fmaf(cw[uo], cr[i], acc[uo][i][0]);
                        acc[uo][i][1] = fmaf(cw[uo], ci[i], acc[uo][i][1]);
                    }
            }
        }

        // ---- orientation -1: U = u(x-e_a,a); neighbor w at bsm ----
        {
            const float* __restrict__ Um = u + (size_t)bsm * (4 * MAT) + a * MAT;
            float U[MAT];
            if ((a & 1) == 0) load_mat18<0>(Um, U);
            else              load_mat18<1>(Um, U);

            // d = column j of U (no conj)
            float vr[3], vi[3];
#pragma unroll
            for (int k = 0; k < 3; ++k) {
                float2 e = *(const float2*)(Um + (k * NCOL + j) * 2);
                vr[k] = e.x;
                vi[k] = e.y;
            }
            const float* __restrict__ wn = w + (size_t)bsm * (N_IN * MAT);
#pragma unroll
            for (int t = 0; t < 2; ++t) {
                const int v = 2 * h + t;
                float Wn[MAT];
                if ((t & 1) == 0) { if (h == 0) load_mat18<0>(wn + 0*MAT, Wn); else load_mat18<0>(wn + 2*MAT, Wn); }
                else              { if (h == 0) load_mat18<1>(wn + 1*MAT, Wn); else load_mat18<1>(wn + 3*MAT, Wn); }

                float yr[3], yi[3];
#pragma unroll
                for (int i = 0; i < NCOL; ++i) {
                    float sr = 0.f, si = 0.f;
#pragma unroll
                    for (int k = 0; k < NCOL; ++k) {
                        float wr = Wn[(i*3+k)*2], wi = Wn[(i*3+k)*2+1];
                        sr = fmaf(wr, vr[k], sr); sr = fmaf(-wi, vi[k], sr);
                        si = fmaf(wr, vi[k], si); si = fmaf(wi, vr[k], si);
                    }
                    yr[i] = sr; yi[i] = si;
                }
                float cr[3], ci[3];
#pragma unroll
                for (int i = 0; i < NCOL; ++i) {
                    float sr = 0.f, si = 0.f;
#pragma unroll
                    for (int k = 0; k < NCOL; ++k) {
                        float ur = U[(k*3+i)*2], ui = U[(k*3+i)*2+1];
                        sr = fmaf(ur, yr[k], sr); sr = fmaf(ui, yi[k], sr);
                        si = fmaf(ur, yi[k], si); si = fmaf(-ui, yr[k], si);
                    }
                    cr[i] = sr; ci[i] = si;
                }
                const int ch = (5 + a) * 4 + v;
                float4 lo = *(const float4*)&wT[ch][0];
                float4 hi = *(const float4*)&wT[ch][4];
                const float cw[8] = {lo.x, lo.y, lo.z, lo.w, hi.x, hi.y, hi.z, hi.w};
#pragma unroll
                for (int uo = 0; uo < N_OUT; ++uo)
#pragma unroll
                    for (int i = 0; i < NCOL; ++i) {
                        acc[uo][i][0] = fmaf(cw[uo], cr[i], acc[uo][i][0]);
                        acc[uo][i][1] = fmaf(cw[uo], ci[i], acc[uo][i][1]);
                    }
            }
        }
    }

    // ---- pair exchange via shuffle: partner is adjacent lane (h^1) ----
    // I send my partials for the partner's channel-half, receive theirs,
    // and store my half: channels [4h, 4h+4).
    float* __restrict__ obase = out + (size_t)OUT_U + (size_t)bs * (N_OUT * MAT);
    float4 idq = *(const float4*)&wT[36][4 * h];
    const float cid[4] = {idq.x, idq.y, idq.z, idq.w};

#pragma unroll
    for (int t = 0; t < 4; ++t)
#pragma unroll
        for (int i = 0; i < 3; ++i) {
            float sr = h ? acc[t][i][0] : acc[4 + t][i][0];   // partner's half (cndmask on live regs)
            float si = h ? acc[t][i][1] : acc[4 + t][i][1];
            float rr = __shfl_xor(sr, 1);
            float ri = __shfl_xor(si, 1);
            float mr = h ? acc[4 + t][i][0] : acc[t][i][0];   // my half
            float mi = h ? acc[4 + t][i][1] : acc[t][i][1];
            float2 e;
            e.x = mr + rr + ((i == j) ? cid[t] : 0.f);
            e.y = mi + ri;
            *(float2*)(obase + (4 * h + t) * MAT + (i * NCOL + j) * 2) = e;
        }
}

} // namespace

extern "C" void kernel_launch(void* const* d_in, const int* in_sizes, int n_in,
                              void* d_out, int out_size, void* d_ws, size_t ws_size,
                              hipStream_t stream)
{
    const float* u   = (const float*)d_in[0];
    const float* w   = (const float*)d_in[1];
    const float* wgt = (const float*)d_in[2];
    float* out = (float*)d_out;

    // u passthrough: OUT_U/4 float4 = 1179648; 1152 blocks * 256 thr * 4 f4 exact
    copy_kernel<<<dim3(OUT_U / 16 / 256), dim3(256), 0, stream>>>(
        (const float4*)u, (float4*)out);

    lconv_kernel<<<dim3(NTHREADS / 256), dim3(256), 0, stream>>>(u, w, wgt, out);
}

// Round 7
// 64.865 us; speedup vs baseline: 3.8153x; 3.8153x over previous
//
#include <hip/hip_runtime.h>

namespace {

constexpr int NCOL  = 3;
constexpr int N_IN  = 4;
constexpr int N_OUT = 8;
constexpr int T_W   = 37;
constexpr int NB    = 4;
constexpr int NX    = 16384;
constexpr int MAT   = 18;                // floats per complex 3x3
constexpr int NTHREADS = NB * NX * 3;    // one thread per (site, column) — R1 shape
constexpr int OUT_U = NB * NX * 4 * MAT;

__device__ constexpr int SH[4] = {11, 8, 4, 0};
__device__ constexpr int DD[4] = {8, 8, 16, 16};
__device__ constexpr int SS[4] = {2048, 256, 16, 1};

// Matrix base = 72 bytes * idx: 16B-alignment parity = idx&1 (compile-time).
template<int PAR>
__device__ __forceinline__ void load_mat18(const float* __restrict__ p, float* M) {
    if constexpr (PAR == 0) {
        float4 q0 = *(const float4*)(p + 0);
        float4 q1 = *(const float4*)(p + 4);
        float4 q2 = *(const float4*)(p + 8);
        float4 q3 = *(const float4*)(p + 12);
        float2 q4 = *(const float2*)(p + 16);
        M[0]=q0.x;  M[1]=q0.y;  M[2]=q0.z;  M[3]=q0.w;
        M[4]=q1.x;  M[5]=q1.y;  M[6]=q1.z;  M[7]=q1.w;
        M[8]=q2.x;  M[9]=q2.y;  M[10]=q2.z; M[11]=q2.w;
        M[12]=q3.x; M[13]=q3.y; M[14]=q3.z; M[15]=q3.w;
        M[16]=q4.x; M[17]=q4.y;
    } else {
        float2 q4 = *(const float2*)(p + 0);
        float4 q0 = *(const float4*)(p + 2);
        float4 q1 = *(const float4*)(p + 6);
        float4 q2 = *(const float4*)(p + 10);
        float4 q3 = *(const float4*)(p + 14);
        M[0]=q4.x;  M[1]=q4.y;
        M[2]=q0.x;  M[3]=q0.y;  M[4]=q0.z;  M[5]=q0.w;
        M[6]=q1.x;  M[7]=q1.y;  M[8]=q1.z;  M[9]=q1.w;
        M[10]=q2.x; M[11]=q2.y; M[12]=q2.z; M[13]=q2.w;
        M[14]=q3.x; M[15]=q3.y; M[16]=q3.z; M[17]=q3.w;
    }
}

// y = W * d (complex 3x3 times 3-vector)
__device__ __forceinline__ void matvec(const float W[18], const float vr[3], const float vi[3],
                                       float yr[3], float yi[3]) {
#pragma unroll
    for (int i = 0; i < 3; ++i) {
        float sr = 0.f, si = 0.f;
#pragma unroll
        for (int k = 0; k < 3; ++k) {
            float wr = W[(i*3+k)*2], wi = W[(i*3+k)*2+1];
            sr = fmaf(wr, vr[k], sr); sr = fmaf(-wi, vi[k], sr);
            si = fmaf(wr, vi[k], si); si = fmaf(wi, vr[k], si);
        }
        yr[i] = sr; yi[i] = si;
    }
}

__global__ __launch_bounds__(256) void lconv_kernel(
    const float* __restrict__ u,
    const float* __restrict__ w,
    const float* __restrict__ wgt,
    float* __restrict__ out)
{
    __shared__ float wT[T_W][N_OUT];   // wT[v][uo] = wgt[uo*37+v]
    const int tid = threadIdx.x;
    for (int idx = tid; idx < T_W * N_OUT; idx += 256) {
        wT[idx >> 3][idx & 7] = wgt[(idx & 7) * T_W + (idx >> 3)];
    }
    __syncthreads();

    const int gid = blockIdx.x * 256 + tid;

    // fused coalesced copy of u -> out[0:OUT_U): 196608 threads * 6 float4 exact
    {
        const float4* __restrict__ u4 = (const float4*)u;
        float4* __restrict__ o4 = (float4*)out;
#pragma unroll
        for (int k = 0; k < 6; ++k) {
            int idx = gid + k * NTHREADS;
            o4[idx] = u4[idx];
        }
    }

    const int j  = gid % 3;        // matrix column this thread owns
    const int bs = gid / 3;        // b*NX + x
    const int x  = bs & (NX - 1);

    const float* __restrict__ ubase = u + (size_t)bs * (4 * MAT);
    const float* __restrict__ wbase = w + (size_t)bs * (N_IN * MAT);

    float acc[N_OUT][NCOL][2];
#pragma unroll
    for (int uo = 0; uo < N_OUT; ++uo)
#pragma unroll
        for (int i = 0; i < NCOL; ++i) { acc[uo][i][0] = 0.f; acc[uo][i][1] = 0.f; }

    // ---------------- term 0: w itself ----------------
#pragma unroll
    for (int v = 0; v < N_IN; ++v) {
        float4 lo = *(const float4*)&wT[v][0];
        float4 hi = *(const float4*)&wT[v][4];
        const float cw[8] = {lo.x, lo.y, lo.z, lo.w, hi.x, hi.y, hi.z, hi.w};
#pragma unroll
        for (int i = 0; i < NCOL; ++i) {
            float2 e = *(const float2*)(wbase + v * MAT + (i * NCOL + j) * 2);
#pragma unroll
            for (int uo = 0; uo < N_OUT; ++uo) {
                acc[uo][i][0] = fmaf(cw[uo], e.x, acc[uo][i][0]);
                acc[uo][i][1] = fmaf(cw[uo], e.y, acc[uo][i][1]);
            }
        }
    }

    // ------- transported terms: both orientations of each axis interleaved -------
#pragma unroll
    for (int a = 0; a < 4; ++a) {
        const int ca = (x >> SH[a]) & (DD[a] - 1);
        const int xp = (ca == DD[a] - 1) ? x - (DD[a] - 1) * SS[a] : x + SS[a];
        const int xm = (ca == 0)         ? x + (DD[a] - 1) * SS[a] : x - SS[a];
        const int bsp = bs - x + xp;
        const int bsm = bs - x + xm;

        const float* __restrict__ Up = ubase + a * MAT;                       // U_a(x)
        const float* __restrict__ Um = u + (size_t)bsm * (4 * MAT) + a * MAT; // U_a(x-e_a)

        float UP[MAT], UM[MAT];
        if ((a & 1) == 0) { load_mat18<0>(Up, UP); load_mat18<0>(Um, UM); }
        else              { load_mat18<1>(Up, UP); load_mat18<1>(Um, UM); }

        // d+ = conj(row j of U+);  d- = column j of U-   (L1-hit loads, no reg indexing)
        float vpr[3], vpi[3], vmr[3], vmi[3];
#pragma unroll
        for (int k = 0; k < 3; ++k) {
            float2 ep = *(const float2*)(Up + (j * NCOL + k) * 2);
            float2 em = *(const float2*)(Um + (k * NCOL + j) * 2);
            vpr[k] = ep.x; vpi[k] = -ep.y;
            vmr[k] = em.x; vmi[k] =  em.y;
        }

        const float* __restrict__ wp = w + (size_t)bsp * (N_IN * MAT);
        const float* __restrict__ wm = w + (size_t)bsm * (N_IN * MAT);

#pragma unroll
        for (int v = 0; v < N_IN; ++v) {
            // issue both W loads, then compute both transports (each hides the other)
            float WP[MAT], WM[MAT];
            if ((v & 1) == 0) { load_mat18<0>(wp + v * MAT, WP); load_mat18<0>(wm + v * MAT, WM); }
            else              { load_mat18<1>(wp + v * MAT, WP); load_mat18<1>(wm + v * MAT, WM); }

            float ypr[3], ypi[3], ymr[3], ymi[3];
            matvec(WP, vpr, vpi, ypr, ypi);
            matvec(WM, vmr, vmi, ymr, ymi);

            // c+ = U+ * y+   (rows of U+)
            float cpr[3], cpi[3];
#pragma unroll
            for (int i = 0; i < NCOL; ++i) {
                float sr = 0.f, si = 0.f;
#pragma unroll
                for (int k = 0; k < NCOL; ++k) {
                    float ur = UP[(i*3+k)*2], ui = UP[(i*3+k)*2+1];
                    sr = fmaf(ur, ypr[k], sr); sr = fmaf(-ui, ypi[k], sr);
                    si = fmaf(ur, ypi[k], si); si = fmaf(ui, ypr[k], si);
                }
                cpr[i] = sr; cpi[i] = si;
            }
            // c- = U-^H * y-  (conj columns of U-)
            float cmr[3], cmi[3];
#pragma unroll
            for (int i = 0; i < NCOL; ++i) {
                float sr = 0.f, si = 0.f;
#pragma unroll
                for (int k = 0; k < NCOL; ++k) {
                    float ur = UM[(k*3+i)*2], ui = UM[(k*3+i)*2+1];
                    sr = fmaf(ur, ymr[k], sr); sr = fmaf(ui, ymi[k], sr);
                    si = fmaf(ur, ymi[k], si); si = fmaf(-ui, ymr[k], si);
                }
                cmr[i] = sr; cmi[i] = si;
            }

            // mix both into the 8 outputs (channel ids unroll-constant)
            {
                const int chp = (1 + a) * 4 + v;
                float4 lo = *(const float4*)&wT[chp][0];
                float4 hi = *(const float4*)&wT[chp][4];
                const float cw[8] = {lo.x, lo.y, lo.z, lo.w, hi.x, hi.y, hi.z, hi.w};
#pragma unroll
                for (int uo = 0; uo < N_OUT; ++uo)
#pragma unroll
                    for (int i = 0; i < NCOL; ++i) {
                        acc[uo][i][0] = fmaf(cw[uo], cpr[i], acc[uo][i][0]);
                        acc[uo][i][1] = fmaf(cw[uo], cpi[i], acc[uo][i][1]);
                    }
            }
            {
                const int chm = (5 + a) * 4 + v;
                float4 lo = *(const float4*)&wT[chm][0];
                float4 hi = *(const float4*)&wT[chm][4];
                const float cw[8] = {lo.x, lo.y, lo.z, lo.w, hi.x, hi.y, hi.z, hi.w};
#pragma unroll
                for (int uo = 0; uo < N_OUT; ++uo)
#pragma unroll
                    for (int i = 0; i < NCOL; ++i) {
                        acc[uo][i][0] = fmaf(cw[uo], cmr[i], acc[uo][i][0]);
                        acc[uo][i][1] = fmaf(cw[uo], cmi[i], acc[uo][i][1]);
                    }
            }
        }
    }

    // ---------------- store (fold in identity term, channel 36) ----------------
    float cid[N_OUT];
#pragma unroll
    for (int uo = 0; uo < N_OUT; ++uo) cid[uo] = wT[36][uo];

    float* __restrict__ obase = out + (size_t)OUT_U + (size_t)bs * (N_OUT * MAT);
#pragma unroll
    for (int uo = 0; uo < N_OUT; ++uo)
#pragma unroll
        for (int i = 0; i < NCOL; ++i) {
            float2 e;
            e.x = acc[uo][i][0] + ((i == j) ? cid[uo] : 0.f);
            e.y = acc[uo][i][1];
            *(float2*)(obase + uo * MAT + (i * NCOL + j) * 2) = e;
        }
}

} // namespace

extern "C" void kernel_launch(void* const* d_in, const int* in_sizes, int n_in,
                              void* d_out, int out_size, void* d_ws, size_t ws_size,
                              hipStream_t stream)
{
    const float* u   = (const float*)d_in[0];
    const float* w   = (const float*)d_in[1];
    const float* wgt = (const float*)d_in[2];
    float* out = (float*)d_out;

    dim3 block(256);
    dim3 grid(NTHREADS / 256);   // 768 blocks, exact cover
    lconv_kernel<<<grid, block, 0, stream>>>(u, w, wgt, out);
}